// Round 20
// baseline (111.377 us; speedup 1.0000x reference)
//
#include <hip/hip_runtime.h>

typedef __attribute__((ext_vector_type(8))) short bh8;    // 8 bf16 (4 VGPRs)
typedef __attribute__((ext_vector_type(4))) float f32x4;  // 4 fp32
typedef __attribute__((ext_vector_type(16))) float f32x16;// 16 fp32 (32x32 acc)
typedef unsigned short u16;

#define MFMA16 __builtin_amdgcn_mfma_f32_16x16x32_bf16
#define MFMA32 __builtin_amdgcn_mfma_f32_32x32x16_bf16

#if __has_builtin(__builtin_amdgcn_exp2f)
#define EXP2(x) __builtin_amdgcn_exp2f(x)
#else
#define EXP2(x) exp2f(x)
#endif

// softmax scale folded with log2(e): exp(s*0.125) = exp2(s*CEXP).
// CEXP is PRE-FOLDED into the stored q values (gemm<0> epilogue), so the
// attention kernel computes p = exp2(sa) directly; shift dropped
// (normalization is shift-invariant; scores*CEXP ~ [-1,1], p <= ~2).
#define CEXP 0.18033688011112042f

__device__ __forceinline__ u16 f2bf(float f) {
  union { float f; unsigned u; } v; v.f = f;
  unsigned r = v.u + 0x7fffu + ((v.u >> 16) & 1u);
  return (u16)(r >> 16);
}

// v_cvt_pk_bf16_f32: dst.lo16 = bf16(lo), dst.hi16 = bf16(hi), RNE
__device__ __forceinline__ unsigned cvtpk(float lo, float hi) {
  unsigned r;
  asm("v_cvt_pk_bf16_f32 %0, %1, %2" : "=v"(r) : "v"(lo), "v"(hi));
  return r;
}

// v_permlane32_swap_b32 d, s:  d <- {d.lo32lanes, s.lo32lanes},
//                              s <- {d.hi32lanes, s.hi32lanes}
__device__ __forceinline__ void plswap(unsigned &a, unsigned &b) {
  asm("v_permlane32_swap_b32 %0, %1" : "+v"(a), "+v"(b));
}

__device__ __forceinline__ void gload16(void* lds, const void* g) {
  __builtin_amdgcn_global_load_lds(
      (const __attribute__((address_space(1))) unsigned int*)g,
      (__attribute__((address_space(3))) unsigned int*)lds, 16, 0, 0);
}

// ---------------- LayerNorm: one wave per row of 512 fp32 -> bf16 ----------
__global__ __launch_bounds__(256) void k_ln(const float* __restrict__ x,
                                            const float* __restrict__ gamma,
                                            const float* __restrict__ beta,
                                            u16* __restrict__ xn) {
  int row  = blockIdx.x * 4 + (threadIdx.x >> 6);
  int lane = threadIdx.x & 63;
  const float4* xr = (const float4*)(x + row * 512);
  float4 a = xr[lane * 2], b = xr[lane * 2 + 1];
  float s  = a.x + a.y + a.z + a.w + b.x + b.y + b.z + b.w;
  float ss = a.x*a.x + a.y*a.y + a.z*a.z + a.w*a.w
           + b.x*b.x + b.y*b.y + b.z*b.z + b.w*b.w;
#pragma unroll
  for (int m = 1; m < 64; m <<= 1) { s += __shfl_xor(s, m, 64); ss += __shfl_xor(ss, m, 64); }
  float mu  = s * (1.0f / 512.0f);
  float var = ss * (1.0f / 512.0f) - mu * mu;
  float rstd = rsqrtf(var + 1e-5f);
  const float4* g4 = (const float4*)gamma;
  const float4* b4 = (const float4*)beta;
  float4 g0 = g4[lane * 2], g1 = g4[lane * 2 + 1];
  float4 e0 = b4[lane * 2], e1 = b4[lane * 2 + 1];
  bh8 ov;
  ov[0] = (short)f2bf((a.x - mu) * rstd * g0.x + e0.x);
  ov[1] = (short)f2bf((a.y - mu) * rstd * g0.y + e0.y);
  ov[2] = (short)f2bf((a.z - mu) * rstd * g0.z + e0.z);
  ov[3] = (short)f2bf((a.w - mu) * rstd * g0.w + e0.w);
  ov[4] = (short)f2bf((b.x - mu) * rstd * g1.x + e1.x);
  ov[5] = (short)f2bf((b.y - mu) * rstd * g1.y + e1.y);
  ov[6] = (short)f2bf((b.z - mu) * rstd * g1.z + e1.z);
  ov[7] = (short)f2bf((b.w - mu) * rstd * g1.w + e1.w);
  *(bh8*)(xn + row * 512 + lane * 8) = ov;
}

// -------- transpose + cast: in (R,C) f32 row-major -> out (C,R) bf16 -------
__global__ __launch_bounds__(256) void k_transpose_cast(const float* __restrict__ in,
                                                        u16* __restrict__ out,
                                                        int R, int C) {
  __shared__ float tile[32][33];
  int c0 = blockIdx.x * 32, r0 = blockIdx.y * 32;
  int tx = threadIdx.x & 31, ty = threadIdx.x >> 5;
#pragma unroll
  for (int i = 0; i < 32; i += 8)
    tile[ty + i][tx] = in[(r0 + ty + i) * C + (c0 + tx)];
  __syncthreads();
#pragma unroll
  for (int i = 0; i < 32; i += 8)
    out[(c0 + ty + i) * R + (r0 + tx)] = f2bf(tile[tx][ty + i]);
}

// ---------------- GEMM: A (M,512) bf16 @ Bt (N,512) bf16 -------------------
// T1: bijective XCD swizzle on blockIdx (grid % 8 == 0 for both instances).
// EPI==0: q (scaled by CEXP) / k scattered bf16 [bh][t][d]; V written
// DIRECTLY as Vt [bh][d][t] (packed uint2) -- repack kernel fused away.
template <int EPI>
__global__ __launch_bounds__(256) void k_gemm(const u16* __restrict__ A,
                                              const u16* __restrict__ Bt,
                                              int N,
                                              u16* __restrict__ q, u16* __restrict__ kk, u16* __restrict__ vt,
                                              const float* __restrict__ bias,
                                              const float* __restrict__ resid,
                                              float* __restrict__ outp) {
  constexpr int K = 512, BM = 128, BK = 64;
  __shared__ u16 Al[BM * BK];
  __shared__ u16 Bl[BM * BK];
  int nBN = N / 128;
  int bid = (blockIdx.x & 7) * (gridDim.x >> 3) + (blockIdx.x >> 3);
  int m0 = (bid / nBN) * BM;
  int n0 = (bid % nBN) * 128;
  int tid = threadIdx.x, lane = tid & 63, w = tid >> 6;
  int l16 = lane & 15, lh = lane >> 4;
  int wm = (w >> 1) * 64, wn = (w & 1) * 64;
  const u16* Ab = A + m0 * K;
  const u16* Bb = Bt + n0 * K;
  f32x4 acc[4][4];
#pragma unroll
  for (int i = 0; i < 4; ++i)
#pragma unroll
    for (int j = 0; j < 4; ++j) acc[i][j] = (f32x4){0.f, 0.f, 0.f, 0.f};
  int srow = tid >> 3, schunk = tid & 7;
  for (int k0 = 0; k0 < K; k0 += BK) {
    __syncthreads();
#pragma unroll
    for (int j = 0; j < 4; ++j) {
      int r = j * 32 + srow;
      int sc = ((schunk ^ (r & 7)) << 3);
      gload16((char*)Al + j * 4096 + tid * 16, Ab + r * K + k0 + sc);
      gload16((char*)Bl + j * 4096 + tid * 16, Bb + r * K + k0 + sc);
    }
    __syncthreads();
#pragma unroll
    for (int c = 0; c < 2; ++c) {
      bh8 af[4], bf[4];
#pragma unroll
      for (int i = 0; i < 4; ++i) {
        int ra = wm + i * 16 + l16;
        af[i] = *(const bh8*)&Al[ra * 64 + ((c * 32 + lh * 8) ^ ((ra & 7) << 3))];
        int rb = wn + i * 16 + l16;
        bf[i] = *(const bh8*)&Bl[rb * 64 + ((c * 32 + lh * 8) ^ ((rb & 7) << 3))];
      }
#pragma unroll
      for (int mi = 0; mi < 4; ++mi)
#pragma unroll
        for (int ni = 0; ni < 4; ++ni)
          acc[mi][ni] = MFMA16(af[mi], bf[ni], acc[mi][ni], 0, 0, 0);
    }
  }
  if (EPI == 0) {
#pragma unroll
    for (int mi = 0; mi < 4; ++mi)
#pragma unroll
      for (int ni = 0; ni < 4; ++ni) {
        int col = n0 + wn + ni * 16 + l16;
        int s = col >> 9, h = (col >> 6) & 7, d = col & 63;   // s,h uniform
        int row0 = m0 + wm + mi * 16 + lh * 4;
        int b = row0 >> 12, t0 = row0 & 4095;
        if (s == 2) {
          // V -> Vt[bh][d][t], 4 consecutive t packed as uint2
          uint2 pk;
          pk.x = cvtpk(acc[mi][ni][0], acc[mi][ni][1]);
          pk.y = cvtpk(acc[mi][ni][2], acc[mi][ni][3]);
          *(uint2*)&vt[((size_t)((b << 3) + h) * 64 + d) * 4096 + t0] = pk;
        } else if (s == 0) {
          // q scaled by CEXP (softmax scale * log2e folded in)
#pragma unroll
          for (int j = 0; j < 4; ++j)
            q[(((size_t)(b << 3) + h) * 4096 + t0 + j) * 64 + d] =
                f2bf(acc[mi][ni][j] * CEXP);
        } else {
#pragma unroll
          for (int j = 0; j < 4; ++j)
            kk[(((size_t)(b << 3) + h) * 4096 + t0 + j) * 64 + d] = f2bf(acc[mi][ni][j]);
        }
      }
  } else {
#pragma unroll
    for (int mi = 0; mi < 4; ++mi)
#pragma unroll
      for (int ni = 0; ni < 4; ++ni) {
        int col = n0 + wn + ni * 16 + l16;
        float bo = bias[col];
#pragma unroll
        for (int j = 0; j < 4; ++j) {
          int row = m0 + wm + mi * 16 + lh * 4 + j;
          outp[row * 512 + col] = acc[mi][ni][j] + bo + resid[row * 512 + col];
        }
      }
  }
}

// ---------------- Flash attention, causal, hd=64, 32x32 MFMA ---------------
// R20 = R19 with BALANCED qi permutation. The whole grid (1024 blocks,
// 4/CU) is co-resident -- no backfill queue -- and round-robin CU
// assignment gives CU group c blocks tq = {c, c+16, c+32, c+48}. Old desc
// mapping: per-CU tile-sum 156-4c (1.6x imbalance, every CU waits on
// group 0). New mapping qi(g,c) = {63-c, 32+c, 31-c, c}[g=tq>>4] makes the
// per-CU sum exactly 126 for ALL c (bijective over 0..63 per bh; bh->XCD
// locality unchanged since b%8 = bh%8).
__global__ __launch_bounds__(256) void k_attn(const u16* __restrict__ Q,
                                              const u16* __restrict__ Kg,
                                              const u16* __restrict__ Vt,
                                              u16* __restrict__ O) {
  __shared__ u16 Kl[2 * 64 * 64];   // [tile][tk][d], chunk-swizzled
  __shared__ u16 Vl[2 * 64 * 64];   // [tile][d][t],  chunk-swizzled
  int bh = blockIdx.x & 15;
  int tq = blockIdx.x >> 4;          // 0..63
  int g = tq >> 4, c = tq & 15;
  int qi = (g == 0) ? 63 - c : (g == 1) ? 32 + c : (g == 2) ? 31 - c : c;
  int tid = threadIdx.x, lane = tid & 63, w = tid >> 6;
  int l31 = lane & 31, hi = lane >> 5;
  int qh = w >> 1, th = w & 1;
  const u16* Qb = Q + bh * 4096 * 64;
  const u16* Kb = Kg + bh * 4096 * 64;
  const u16* Vb = Vt + (size_t)bh * 64 * 4096;
  int q0 = qi * 64;
  int myq = q0 + qh * 32 + l31;       // this lane's q-column
  bh8 qf[4];                          // Q[myq][ks*16 + hi*8 .. +8]
#pragma unroll
  for (int ks = 0; ks < 4; ++ks)
    qf[ks] = *(const bh8*)(Qb + myq * 64 + ks * 16 + hi * 8);
  float l_ = 0.f;                     // lane-partial sum for q = myq
  f32x16 acc[2];                      // O-partial [q=row(r,hi)][d=dh*32+l31]
#pragma unroll
  for (int dh = 0; dh < 2; ++dh)
#pragma unroll
    for (int r = 0; r < 16; ++r) acc[dh][r] = 0.f;
  int srow = tid >> 3, schunk = tid & 7;

  for (int kt = 0; kt <= qi; kt += 2) {
    __syncthreads();                     // prev readers done
#pragma unroll
    for (int t = 0; t < 2; ++t) {
      int kb = (kt + t) * 64;            // max staged row 4095, in bounds
#pragma unroll
      for (int j = 0; j < 2; ++j) {
        int r = j * 32 + srow;
        int sc = ((schunk ^ (r & 7)) << 3);
        gload16((char*)Kl + t * 8192 + j * 4096 + tid * 16, Kb + (kb + r) * 64 + sc);
        gload16((char*)Vl + t * 8192 + j * 4096 + tid * 16, Vb + r * 4096 + kb + sc);
      }
    }
    __syncthreads();                     // drains gload_lds + barrier
#pragma unroll
    for (int t = 0; t < 2; ++t) {
      int kz = kt + t;
      const u16* Kc = Kl + t * 4096;
      const u16* Vc = Vl + t * 4096;
      // ---- QK: S^T quadrant = K[th-half] @ Q^T[qh-half], 4 MFMA over d ----
      f32x16 sa;
#pragma unroll
      for (int r = 0; r < 16; ++r) sa[r] = 0.f;
      int rk = th * 32 + l31;            // this lane's K row (tk local in tile)
      __builtin_amdgcn_s_setprio(1);
#pragma unroll
      for (int ks = 0; ks < 4; ++ks) {
        int ck = ks * 2 + hi;            // d-chunk
        bh8 kf = *(const bh8*)&Kc[rk * 64 + ((ck ^ (rk & 7)) << 3)];
        sa = MFMA32(kf, qf[ks], sa, 0, 0, 0);
      }
      __builtin_amdgcn_s_setprio(0);
      // ---- causal mask (last pair only; fully-masked tiles give p=0) ----
      if (kt + 2 > qi) {
#pragma unroll
        for (int r = 0; r < 16; ++r) {
          int tkg = kz * 64 + th * 32 + (r & 3) + 8 * (r >> 2) + 4 * hi;
          if (tkg > myq) sa[r] = -3e38f;
        }
      }
      // ---- softmax: p = exp2(sa); pack + permlane -> in-reg A-frags ----
      float p[16];
#pragma unroll
      for (int r = 0; r < 16; ++r) {
        p[r] = EXP2(sa[r]);
        l_ += p[r];
      }
      unsigned Wx[4], Wy[4];
#pragma unroll
      for (int u = 0; u < 4; ++u) {
        Wx[u] = cvtpk(p[4 * u + 0], p[4 * u + 1]);
        Wy[u] = cvtpk(p[4 * u + 2], p[4 * u + 3]);
      }
      bh8 paf[2];
#pragma unroll
      for (int k2 = 0; k2 < 2; ++k2) {
        unsigned d0 = Wx[2 * k2], d1 = Wy[2 * k2];
        unsigned s0 = Wx[2 * k2 + 1], s1 = Wy[2 * k2 + 1];
        plswap(d0, s0);
        plswap(d1, s1);
        union { unsigned u[4]; bh8 h; } cvu;
        cvu.u[0] = d0; cvu.u[1] = d1; cvu.u[2] = s0; cvu.u[3] = s1;
        paf[k2] = cvu.h;
      }
      // ---- PV: O-partial += P[32q x 32tk] @ V[32tk x 64d] ----
      __builtin_amdgcn_s_setprio(1);
#pragma unroll
      for (int dh = 0; dh < 2; ++dh) {
        int rv = dh * 32 + l31;          // V d-row
#pragma unroll
        for (int k2 = 0; k2 < 2; ++k2) {
          int cv = th * 4 + k2 * 2 + hi; // V t-chunk
          bh8 vb = *(const bh8*)&Vc[rv * 64 + ((cv ^ (rv & 7)) << 3)];
          acc[dh] = MFMA32(paf[k2], vb, acc[dh], 0, 0, 0);
        }
      }
      __builtin_amdgcn_s_setprio(0);
    }
  }
  // ---- epilogue: merge th-halves via LDS (aliased over Kl/Vl) ----
  __syncthreads();                       // everyone done with Kl/Vl
  float* Ow = (float*)Kl;                // [qh][32 q][64 d] f32 = 16KB
  float* Lw = (float*)Vl;                // [qh*2+th][32] f32
  float* Iw = (float*)Vl + 128;          // [qh][32] f32
  l_ += __shfl_xor(l_, 32, 64);          // combine hi halves (same q)
  if (hi == 0) Lw[(qh * 2 + th) * 32 + l31] = l_;
  if (th == 0) {
#pragma unroll
    for (int dh = 0; dh < 2; ++dh)
#pragma unroll
      for (int r = 0; r < 16; ++r) {
        int row = (r & 3) + 8 * (r >> 2) + 4 * hi;
        Ow[qh * 2048 + row * 64 + dh * 32 + l31] = acc[dh][r];
      }
  }
  __syncthreads();
  float lt = Lw[(qh * 2) * 32 + l31] + Lw[(qh * 2 + 1) * 32 + l31];
  float invq = 1.0f / lt;
  if (hi == 0) Iw[qh * 32 + l31] = invq;
  __syncthreads();
  if (th == 1) {
    int b = bh >> 3, h = bh & 7;
#pragma unroll
    for (int quad = 0; quad < 4; ++quad) {
      f32x4 iv = *(const f32x4*)&Iw[qh * 32 + quad * 8 + hi * 4];
#pragma unroll
      for (int j = 0; j < 4; ++j) {
        int r = quad * 4 + j;
        int row = j + 8 * quad + 4 * hi;
        int tg = q0 + qh * 32 + row;
#pragma unroll
        for (int dh = 0; dh < 2; ++dh) {
          float o = acc[dh][r] + Ow[qh * 2048 + row * 64 + dh * 32 + l31];
          O[((size_t)b * 4096 + tg) * 512 + h * 64 + dh * 32 + l31] = f2bf(o * iv[j]);
        }
      }
    }
  }
}

extern "C" void kernel_launch(void* const* d_in, const int* in_sizes, int n_in,
                              void* d_out, int out_size, void* d_ws, size_t ws_size,
                              hipStream_t stream) {
  const float* x     = (const float*)d_in[0];
  const float* w_qkv = (const float*)d_in[1];
  const float* w_out = (const float*)d_in[2];
  const float* b_out = (const float*)d_in[3];
  const float* gamma = (const float*)d_in[4];
  const float* beta  = (const float*)d_in[5];
  float* out = (float*)d_out;
  char* ws = (char*)d_ws;
  u16* xn    = (u16*)(ws);                    // 8 MB  (A of gemm_qkv; reused as attn_out)
  u16* wqkvT = (u16*)(ws + 8388608);          // 1.5 MB
  u16* woutT = (u16*)(ws + 9961472);          // 0.5 MB
  u16* q     = (u16*)(ws + 10485760);         // 8 MB
  u16* k     = (u16*)(ws + 18874368);         // 8 MB
  u16* vt    = (u16*)(ws + 27262976);         // 8 MB  Vt [bh][d][t], written by gemm<0>
  u16* attn_out = xn;                         // xn dead after gemm<0>

  k_ln<<<2048, 256, 0, stream>>>(x, gamma, beta, xn);
  k_transpose_cast<<<dim3(48, 16), 256, 0, stream>>>(w_qkv, wqkvT, 512, 1536);
  k_transpose_cast<<<dim3(16, 16), 256, 0, stream>>>(w_out, woutT, 512, 512);
  k_gemm<0><<<64 * 12, 256, 0, stream>>>(xn, wqkvT, 1536, q, k, vt, nullptr, nullptr, nullptr);
  k_attn<<<1024, 256, 0, stream>>>(q, k, vt, attn_out);
  k_gemm<1><<<64 * 4, 256, 0, stream>>>(attn_out, woutT, 512, nullptr, nullptr, nullptr, b_out, x, out);
}

// Round 21
// 105.132 us; speedup vs baseline: 1.0594x; 1.0594x over previous
//
#include <hip/hip_runtime.h>

typedef __attribute__((ext_vector_type(8))) short bh8;    // 8 bf16 (4 VGPRs)
typedef __attribute__((ext_vector_type(4))) float f32x4;  // 4 fp32
typedef __attribute__((ext_vector_type(16))) float f32x16;// 16 fp32 (32x32 acc)
typedef unsigned short u16;

#define MFMA16 __builtin_amdgcn_mfma_f32_16x16x32_bf16
#define MFMA32 __builtin_amdgcn_mfma_f32_32x32x16_bf16

#if __has_builtin(__builtin_amdgcn_exp2f)
#define EXP2(x) __builtin_amdgcn_exp2f(x)
#else
#define EXP2(x) exp2f(x)
#endif

// softmax scale folded with log2(e): exp(s*0.125) = exp2(s*CEXP).
// CEXP is PRE-FOLDED into the stored q values (gemm<0> epilogue), so the
// attention kernel computes p = exp2(sa) directly; shift dropped
// (normalization is shift-invariant; scores*CEXP ~ [-1,1], p <= ~2).
#define CEXP 0.18033688011112042f

__device__ __forceinline__ u16 f2bf(float f) {
  union { float f; unsigned u; } v; v.f = f;
  unsigned r = v.u + 0x7fffu + ((v.u >> 16) & 1u);
  return (u16)(r >> 16);
}

// v_cvt_pk_bf16_f32: dst.lo16 = bf16(lo), dst.hi16 = bf16(hi), RNE
__device__ __forceinline__ unsigned cvtpk(float lo, float hi) {
  unsigned r;
  asm("v_cvt_pk_bf16_f32 %0, %1, %2" : "=v"(r) : "v"(lo), "v"(hi));
  return r;
}

// v_permlane32_swap_b32 d, s:  d <- {d.lo32lanes, s.lo32lanes},
//                              s <- {d.hi32lanes, s.hi32lanes}
__device__ __forceinline__ void plswap(unsigned &a, unsigned &b) {
  asm("v_permlane32_swap_b32 %0, %1" : "+v"(a), "+v"(b));
}

__device__ __forceinline__ void gload16(void* lds, const void* g) {
  __builtin_amdgcn_global_load_lds(
      (const __attribute__((address_space(1))) unsigned int*)g,
      (__attribute__((address_space(3))) unsigned int*)lds, 16, 0, 0);
}

// ---------------- Fused prep: LN (blocks 0..2047) + weight transposes ------
// blocks 2048..2815: w_qkv (512,1536) -> wqkvT (1536,512) bf16
// blocks 2816..3071: w_out (512, 512) -> woutT  (512,512) bf16
// All sections independent (no cross-block deps); one dispatch saves two
// launch gaps and overlaps the transposes with LN's memory-bound tail.
__global__ __launch_bounds__(256) void k_prep(const float* __restrict__ x,
                                              const float* __restrict__ gamma,
                                              const float* __restrict__ beta,
                                              u16* __restrict__ xn,
                                              const float* __restrict__ w_qkv,
                                              u16* __restrict__ wqkvT,
                                              const float* __restrict__ w_out,
                                              u16* __restrict__ woutT) {
  __shared__ float tile[32][33];
  int bx = blockIdx.x;
  if (bx < 2048) {
    // ---- LayerNorm: one wave per row of 512 fp32 -> bf16 ----
    int row  = bx * 4 + (threadIdx.x >> 6);
    int lane = threadIdx.x & 63;
    const float4* xr = (const float4*)(x + row * 512);
    float4 a = xr[lane * 2], b = xr[lane * 2 + 1];
    float s  = a.x + a.y + a.z + a.w + b.x + b.y + b.z + b.w;
    float ss = a.x*a.x + a.y*a.y + a.z*a.z + a.w*a.w
             + b.x*b.x + b.y*b.y + b.z*b.z + b.w*b.w;
#pragma unroll
    for (int m = 1; m < 64; m <<= 1) { s += __shfl_xor(s, m, 64); ss += __shfl_xor(ss, m, 64); }
    float mu  = s * (1.0f / 512.0f);
    float var = ss * (1.0f / 512.0f) - mu * mu;
    float rstd = rsqrtf(var + 1e-5f);
    const float4* g4 = (const float4*)gamma;
    const float4* b4 = (const float4*)beta;
    float4 g0 = g4[lane * 2], g1 = g4[lane * 2 + 1];
    float4 e0 = b4[lane * 2], e1 = b4[lane * 2 + 1];
    bh8 ov;
    ov[0] = (short)f2bf((a.x - mu) * rstd * g0.x + e0.x);
    ov[1] = (short)f2bf((a.y - mu) * rstd * g0.y + e0.y);
    ov[2] = (short)f2bf((a.z - mu) * rstd * g0.z + e0.z);
    ov[3] = (short)f2bf((a.w - mu) * rstd * g0.w + e0.w);
    ov[4] = (short)f2bf((b.x - mu) * rstd * g1.x + e1.x);
    ov[5] = (short)f2bf((b.y - mu) * rstd * g1.y + e1.y);
    ov[6] = (short)f2bf((b.z - mu) * rstd * g1.z + e1.z);
    ov[7] = (short)f2bf((b.w - mu) * rstd * g1.w + e1.w);
    *(bh8*)(xn + row * 512 + lane * 8) = ov;
  } else {
    const float* in;
    u16* out;
    int R = 512, C, c0, r0;
    if (bx < 2816) {
      int i = bx - 2048;               // 48 x 16
      in = w_qkv; out = wqkvT; C = 1536;
      c0 = (i % 48) * 32; r0 = (i / 48) * 32;
    } else {
      int i = bx - 2816;               // 16 x 16
      in = w_out; out = woutT; C = 512;
      c0 = (i % 16) * 32; r0 = (i / 16) * 32;
    }
    int tx = threadIdx.x & 31, ty = threadIdx.x >> 5;
#pragma unroll
    for (int i2 = 0; i2 < 32; i2 += 8)
      tile[ty + i2][tx] = in[(r0 + ty + i2) * C + (c0 + tx)];
    __syncthreads();
#pragma unroll
    for (int i2 = 0; i2 < 32; i2 += 8)
      out[(c0 + ty + i2) * R + (r0 + tx)] = f2bf(tile[tx][ty + i2]);
  }
}

// ---------------- GEMM: A (M,512) bf16 @ Bt (N,512) bf16 -------------------
// T1: bijective XCD swizzle on blockIdx (grid % 8 == 0 for both instances).
// EPI==0: q (scaled by CEXP) / k scattered bf16 [bh][t][d]; V written
// DIRECTLY as Vt [bh][d][t] (packed uint2) -- repack kernel fused away.
template <int EPI>
__global__ __launch_bounds__(256) void k_gemm(const u16* __restrict__ A,
                                              const u16* __restrict__ Bt,
                                              int N,
                                              u16* __restrict__ q, u16* __restrict__ kk, u16* __restrict__ vt,
                                              const float* __restrict__ bias,
                                              const float* __restrict__ resid,
                                              float* __restrict__ outp) {
  constexpr int K = 512, BM = 128, BK = 64;
  __shared__ u16 Al[BM * BK];
  __shared__ u16 Bl[BM * BK];
  int nBN = N / 128;
  int bid = (blockIdx.x & 7) * (gridDim.x >> 3) + (blockIdx.x >> 3);
  int m0 = (bid / nBN) * BM;
  int n0 = (bid % nBN) * 128;
  int tid = threadIdx.x, lane = tid & 63, w = tid >> 6;
  int l16 = lane & 15, lh = lane >> 4;
  int wm = (w >> 1) * 64, wn = (w & 1) * 64;
  const u16* Ab = A + m0 * K;
  const u16* Bb = Bt + n0 * K;
  f32x4 acc[4][4];
#pragma unroll
  for (int i = 0; i < 4; ++i)
#pragma unroll
    for (int j = 0; j < 4; ++j) acc[i][j] = (f32x4){0.f, 0.f, 0.f, 0.f};
  int srow = tid >> 3, schunk = tid & 7;
  for (int k0 = 0; k0 < K; k0 += BK) {
    __syncthreads();
#pragma unroll
    for (int j = 0; j < 4; ++j) {
      int r = j * 32 + srow;
      int sc = ((schunk ^ (r & 7)) << 3);
      gload16((char*)Al + j * 4096 + tid * 16, Ab + r * K + k0 + sc);
      gload16((char*)Bl + j * 4096 + tid * 16, Bb + r * K + k0 + sc);
    }
    __syncthreads();
#pragma unroll
    for (int c = 0; c < 2; ++c) {
      bh8 af[4], bf[4];
#pragma unroll
      for (int i = 0; i < 4; ++i) {
        int ra = wm + i * 16 + l16;
        af[i] = *(const bh8*)&Al[ra * 64 + ((c * 32 + lh * 8) ^ ((ra & 7) << 3))];
        int rb = wn + i * 16 + l16;
        bf[i] = *(const bh8*)&Bl[rb * 64 + ((c * 32 + lh * 8) ^ ((rb & 7) << 3))];
      }
#pragma unroll
      for (int mi = 0; mi < 4; ++mi)
#pragma unroll
        for (int ni = 0; ni < 4; ++ni)
          acc[mi][ni] = MFMA16(af[mi], bf[ni], acc[mi][ni], 0, 0, 0);
    }
  }
  if (EPI == 0) {
#pragma unroll
    for (int mi = 0; mi < 4; ++mi)
#pragma unroll
      for (int ni = 0; ni < 4; ++ni) {
        int col = n0 + wn + ni * 16 + l16;
        int s = col >> 9, h = (col >> 6) & 7, d = col & 63;   // s,h uniform
        int row0 = m0 + wm + mi * 16 + lh * 4;
        int b = row0 >> 12, t0 = row0 & 4095;
        if (s == 2) {
          // V -> Vt[bh][d][t], 4 consecutive t packed as uint2
          uint2 pk;
          pk.x = cvtpk(acc[mi][ni][0], acc[mi][ni][1]);
          pk.y = cvtpk(acc[mi][ni][2], acc[mi][ni][3]);
          *(uint2*)&vt[((size_t)((b << 3) + h) * 64 + d) * 4096 + t0] = pk;
        } else if (s == 0) {
          // q scaled by CEXP (softmax scale * log2e folded in)
#pragma unroll
          for (int j = 0; j < 4; ++j)
            q[(((size_t)(b << 3) + h) * 4096 + t0 + j) * 64 + d] =
                f2bf(acc[mi][ni][j] * CEXP);
        } else {
#pragma unroll
          for (int j = 0; j < 4; ++j)
            kk[(((size_t)(b << 3) + h) * 4096 + t0 + j) * 64 + d] = f2bf(acc[mi][ni][j]);
        }
      }
  } else {
#pragma unroll
    for (int mi = 0; mi < 4; ++mi)
#pragma unroll
      for (int ni = 0; ni < 4; ++ni) {
        int col = n0 + wn + ni * 16 + l16;
        float bo = bias[col];
#pragma unroll
        for (int j = 0; j < 4; ++j) {
          int row = m0 + wm + mi * 16 + lh * 4 + j;
          outp[row * 512 + col] = acc[mi][ni][j] + bo + resid[row * 512 + col];
        }
      }
  }
}

// ---------------- Flash attention, causal, hd=64, 32x32 MFMA ---------------
// R21 = R19 exactly (descending qi -- R20's "balanced" permutation was
// measured WORSE, assignment model falsified). P held in registers via
// cvtpk + v_permlane32_swap (no LDS bounce); q pre-scaled by CEXP so
// softmax is p = exp2(sa); static normalization (shift-invariant).
__global__ __launch_bounds__(256) void k_attn(const u16* __restrict__ Q,
                                              const u16* __restrict__ Kg,
                                              const u16* __restrict__ Vt,
                                              u16* __restrict__ O) {
  __shared__ u16 Kl[2 * 64 * 64];   // [tile][tk][d], chunk-swizzled
  __shared__ u16 Vl[2 * 64 * 64];   // [tile][d][t],  chunk-swizzled
  int bh = blockIdx.x & 15;
  int qi = 63 - (blockIdx.x >> 4);   // descending length for load balance
  int tid = threadIdx.x, lane = tid & 63, w = tid >> 6;
  int l31 = lane & 31, hi = lane >> 5;
  int qh = w >> 1, th = w & 1;
  const u16* Qb = Q + bh * 4096 * 64;
  const u16* Kb = Kg + bh * 4096 * 64;
  const u16* Vb = Vt + (size_t)bh * 64 * 4096;
  int q0 = qi * 64;
  int myq = q0 + qh * 32 + l31;       // this lane's q-column
  bh8 qf[4];                          // Q[myq][ks*16 + hi*8 .. +8]
#pragma unroll
  for (int ks = 0; ks < 4; ++ks)
    qf[ks] = *(const bh8*)(Qb + myq * 64 + ks * 16 + hi * 8);
  float l_ = 0.f;                     // lane-partial sum for q = myq
  f32x16 acc[2];                      // O-partial [q=row(r,hi)][d=dh*32+l31]
#pragma unroll
  for (int dh = 0; dh < 2; ++dh)
#pragma unroll
    for (int r = 0; r < 16; ++r) acc[dh][r] = 0.f;
  int srow = tid >> 3, schunk = tid & 7;

  for (int kt = 0; kt <= qi; kt += 2) {
    __syncthreads();                     // prev readers done
#pragma unroll
    for (int t = 0; t < 2; ++t) {
      int kb = (kt + t) * 64;            // max staged row 4095, in bounds
#pragma unroll
      for (int j = 0; j < 2; ++j) {
        int r = j * 32 + srow;
        int sc = ((schunk ^ (r & 7)) << 3);
        gload16((char*)Kl + t * 8192 + j * 4096 + tid * 16, Kb + (kb + r) * 64 + sc);
        gload16((char*)Vl + t * 8192 + j * 4096 + tid * 16, Vb + r * 4096 + kb + sc);
      }
    }
    __syncthreads();                     // drains gload_lds + barrier
#pragma unroll
    for (int t = 0; t < 2; ++t) {
      int kz = kt + t;
      const u16* Kc = Kl + t * 4096;
      const u16* Vc = Vl + t * 4096;
      // ---- QK: S^T quadrant = K[th-half] @ Q^T[qh-half], 4 MFMA over d ----
      f32x16 sa;
#pragma unroll
      for (int r = 0; r < 16; ++r) sa[r] = 0.f;
      int rk = th * 32 + l31;            // this lane's K row (tk local in tile)
      __builtin_amdgcn_s_setprio(1);
#pragma unroll
      for (int ks = 0; ks < 4; ++ks) {
        int ck = ks * 2 + hi;            // d-chunk
        bh8 kf = *(const bh8*)&Kc[rk * 64 + ((ck ^ (rk & 7)) << 3)];
        sa = MFMA32(kf, qf[ks], sa, 0, 0, 0);
      }
      __builtin_amdgcn_s_setprio(0);
      // ---- causal mask (last pair only; fully-masked tiles give p=0) ----
      if (kt + 2 > qi) {
#pragma unroll
        for (int r = 0; r < 16; ++r) {
          int tkg = kz * 64 + th * 32 + (r & 3) + 8 * (r >> 2) + 4 * hi;
          if (tkg > myq) sa[r] = -3e38f;
        }
      }
      // ---- softmax: p = exp2(sa); pack + permlane -> in-reg A-frags ----
      float p[16];
#pragma unroll
      for (int r = 0; r < 16; ++r) {
        p[r] = EXP2(sa[r]);
        l_ += p[r];
      }
      unsigned Wx[4], Wy[4];
#pragma unroll
      for (int u = 0; u < 4; ++u) {
        Wx[u] = cvtpk(p[4 * u + 0], p[4 * u + 1]);
        Wy[u] = cvtpk(p[4 * u + 2], p[4 * u + 3]);
      }
      bh8 paf[2];
#pragma unroll
      for (int k2 = 0; k2 < 2; ++k2) {
        unsigned d0 = Wx[2 * k2], d1 = Wy[2 * k2];
        unsigned s0 = Wx[2 * k2 + 1], s1 = Wy[2 * k2 + 1];
        plswap(d0, s0);
        plswap(d1, s1);
        union { unsigned u[4]; bh8 h; } cvu;
        cvu.u[0] = d0; cvu.u[1] = d1; cvu.u[2] = s0; cvu.u[3] = s1;
        paf[k2] = cvu.h;
      }
      // ---- PV: O-partial += P[32q x 32tk] @ V[32tk x 64d] ----
      __builtin_amdgcn_s_setprio(1);
#pragma unroll
      for (int dh = 0; dh < 2; ++dh) {
        int rv = dh * 32 + l31;          // V d-row
#pragma unroll
        for (int k2 = 0; k2 < 2; ++k2) {
          int cv = th * 4 + k2 * 2 + hi; // V t-chunk
          bh8 vb = *(const bh8*)&Vc[rv * 64 + ((cv ^ (rv & 7)) << 3)];
          acc[dh] = MFMA32(paf[k2], vb, acc[dh], 0, 0, 0);
        }
      }
      __builtin_amdgcn_s_setprio(0);
    }
  }
  // ---- epilogue: merge th-halves via LDS (aliased over Kl/Vl) ----
  __syncthreads();                       // everyone done with Kl/Vl
  float* Ow = (float*)Kl;                // [qh][32 q][64 d] f32 = 16KB
  float* Lw = (float*)Vl;                // [qh*2+th][32] f32
  float* Iw = (float*)Vl + 128;          // [qh][32] f32
  l_ += __shfl_xor(l_, 32, 64);          // combine hi halves (same q)
  if (hi == 0) Lw[(qh * 2 + th) * 32 + l31] = l_;
  if (th == 0) {
#pragma unroll
    for (int dh = 0; dh < 2; ++dh)
#pragma unroll
      for (int r = 0; r < 16; ++r) {
        int row = (r & 3) + 8 * (r >> 2) + 4 * hi;
        Ow[qh * 2048 + row * 64 + dh * 32 + l31] = acc[dh][r];
      }
  }
  __syncthreads();
  float lt = Lw[(qh * 2) * 32 + l31] + Lw[(qh * 2 + 1) * 32 + l31];
  float invq = 1.0f / lt;
  if (hi == 0) Iw[qh * 32 + l31] = invq;
  __syncthreads();
  if (th == 1) {
    int b = bh >> 3, h = bh & 7;
#pragma unroll
    for (int quad = 0; quad < 4; ++quad) {
      f32x4 iv = *(const f32x4*)&Iw[qh * 32 + quad * 8 + hi * 4];
#pragma unroll
      for (int j = 0; j < 4; ++j) {
        int r = quad * 4 + j;
        int row = j + 8 * quad + 4 * hi;
        int tg = q0 + qh * 32 + row;
#pragma unroll
        for (int dh = 0; dh < 2; ++dh) {
          float o = acc[dh][r] + Ow[qh * 2048 + row * 64 + dh * 32 + l31];
          O[((size_t)b * 4096 + tg) * 512 + h * 64 + dh * 32 + l31] = f2bf(o * iv[j]);
        }
      }
    }
  }
}

extern "C" void kernel_launch(void* const* d_in, const int* in_sizes, int n_in,
                              void* d_out, int out_size, void* d_ws, size_t ws_size,
                              hipStream_t stream) {
  const float* x     = (const float*)d_in[0];
  const float* w_qkv = (const float*)d_in[1];
  const float* w_out = (const float*)d_in[2];
  const float* b_out = (const float*)d_in[3];
  const float* gamma = (const float*)d_in[4];
  const float* beta  = (const float*)d_in[5];
  float* out = (float*)d_out;
  char* ws = (char*)d_ws;
  u16* xn    = (u16*)(ws);                    // 8 MB  (A of gemm_qkv; reused as attn_out)
  u16* wqkvT = (u16*)(ws + 8388608);          // 1.5 MB
  u16* woutT = (u16*)(ws + 9961472);          // 0.5 MB
  u16* q     = (u16*)(ws + 10485760);         // 8 MB
  u16* k     = (u16*)(ws + 18874368);         // 8 MB
  u16* vt    = (u16*)(ws + 27262976);         // 8 MB  Vt [bh][d][t], written by gemm<0>
  u16* attn_out = xn;                         // xn dead after gemm<0>

  k_prep<<<3072, 256, 0, stream>>>(x, gamma, beta, xn, w_qkv, wqkvT, w_out, woutT);
  k_gemm<0><<<64 * 12, 256, 0, stream>>>(xn, wqkvT, 1536, q, k, vt, nullptr, nullptr, nullptr);
  k_attn<<<1024, 256, 0, stream>>>(q, k, vt, attn_out);
  k_gemm<1><<<64 * 4, 256, 0, stream>>>(attn_out, woutT, 512, nullptr, nullptr, nullptr, b_out, x, out);
}